// Round 10
// baseline (978.897 us; speedup 1.0000x reference)
//
#include <hip/hip_runtime.h>
#include <hip/hip_bf16.h>

#define MM   16384
#define NN   65536
#define NNZV 4194304
#define BB   16

#define NB    64                 // hist/scatter blocks
#define IPT   128                // NNZV / (NB*512)
#define NBINS 8192               // bins per pass (both passes)
#define CAP2  192                // per-rowgroup segment capacity (lambda=64, 16 sigma)

// row pass: t1 = A(zu): scatter M (stile 128 rows, 128 stiles x 2 gather-splits),
//           gather N (gtile 1024, 64 gtiles)
// col pass: t2 = A^T(r): scatter N (stile 256 cols, 256 stiles x 2 batch-halves),
//           gather M (gtile 512, 32 gtiles)

// ---------------- zuT[n*16+b] = z[b,n]*u[b,n] ----------------
__global__ void k_zuT(const float* __restrict__ z, const float* __restrict__ u,
                      float* __restrict__ zuT) {
    int n = blockIdx.x * 256 + threadIdx.x;
    float f[BB];
#pragma unroll
    for (int b = 0; b < BB; ++b)
        f[b] = z[(size_t)b * NN + n] * u[(size_t)b * NN + n];
#pragma unroll
    for (int i = 0; i < 4; ++i)
        ((float4*)(zuT + (size_t)n * BB))[i] = ((float4*)f)[i];
}

// ---------------- 2D histogram: bin = (s>>ss)*ngt + (g>>gs) ----------------
__global__ __launch_bounds__(512) void k_hist(const int* __restrict__ sidx,
                                              const int* __restrict__ gidx,
                                              int* __restrict__ cnt,
                                              int ss, int gs, int ngt) {
    __shared__ int h[NBINS];
    for (int i = threadIdx.x; i < NBINS; i += 512) h[i] = 0;
    __syncthreads();
    int base = blockIdx.x * (512 * IPT);
    for (int it = 0; it < IPT; ++it) {
        int k = base + it * 512 + threadIdx.x;
        int bin = (sidx[k] >> ss) * ngt + (gidx[k] >> gs);
        atomicAdd(&h[bin], 1);
    }
    __syncthreads();
    for (int i = threadIdx.x; i < NBINS; i += 512)
        cnt[i * NB + blockIdx.x] = h[i];
}

// ---------------- scan phase A: per-512-chunk exclusive scan ----------------
__global__ __launch_bounds__(512) void k_scanA(int* __restrict__ cnt, int* __restrict__ bsum) {
    __shared__ int s[512];
    int tid = threadIdx.x;
    int v = cnt[blockIdx.x * 512 + tid];
    s[tid] = v;
    __syncthreads();
    for (int off = 1; off < 512; off <<= 1) {
        int t = (tid >= off) ? s[tid - off] : 0;
        __syncthreads();
        s[tid] += t;
        __syncthreads();
    }
    cnt[blockIdx.x * 512 + tid] = s[tid] - v;
    if (tid == 511) bsum[blockIdx.x] = s[511];
}

// ---------------- scan phase B: exclusive scan of 1024 chunk sums ----------
__global__ __launch_bounds__(1024) void k_scanB(int* __restrict__ bsum) {
    __shared__ int s[1024];
    int tid = threadIdx.x;
    int v = bsum[tid];
    s[tid] = v;
    __syncthreads();
    for (int off = 1; off < 1024; off <<= 1) {
        int t = (tid >= off) ? s[tid - off] : 0;
        __syncthreads();
        s[tid] += t;
        __syncthreads();
    }
    bsum[tid] = s[tid] - v;
}

// ---------------- scatter into (stile,gtile) buckets ----------------
// item = (val bits, (g_local << shl) | s_local)
__global__ __launch_bounds__(512) void k_scatter(const int* __restrict__ sidx,
                                                 const int* __restrict__ gidx,
                                                 const float* __restrict__ vals,
                                                 const int* __restrict__ cnt,
                                                 const int* __restrict__ bsum,
                                                 int ss, int gs, int ngt,
                                                 int smask, int gmask, int shl,
                                                 uint2* __restrict__ items) {
    __shared__ int nxt[NBINS];
    for (int i = threadIdx.x; i < NBINS; i += 512) {
        int idx = i * NB + blockIdx.x;
        nxt[i] = cnt[idx] + bsum[idx >> 9];
    }
    __syncthreads();
    int base = blockIdx.x * (512 * IPT);
    for (int it = 0; it < IPT; ++it) {
        int k = base + it * 512 + threadIdx.x;
        int s = sidx[k], g = gidx[k];
        float v = vals[k];
        int bin = (s >> ss) * ngt + (g >> gs);
        int r = atomicAdd(&nxt[bin], 1);
        items[r] = make_uint2(__float_as_uint(v),
                              ((unsigned)(g & gmask) << shl) | (unsigned)(s & smask));
    }
}

// ---------------- row-pass accumulate: wave-owned rowgroups, no sort --------
// 512 thr = 8 waves; wave w owns rows [w*16, w*16+16); lane = (row&15)*4 + quad.
__global__ __launch_bounds__(512) void k_accumR(const uint2* __restrict__ items,
                                                const int* __restrict__ cnt,
                                                const int* __restrict__ bsum,
                                                const float* __restrict__ zuT,
                                                float* __restrict__ part) {
    __shared__ __align__(16) float stage[1024 * 16];   // 64 KB: one gather tile
    __shared__ uint2 seg[8][CAP2];                     // 12 KB
    __shared__ int cur[8];
    __shared__ int offs[33];
    int tid = threadIdx.x, wid = tid >> 6, lane = tid & 63;
    int stile = blockIdx.x >> 1, split = blockIdx.x & 1;
    int fb = stile * 64 + split * 32;
    if (tid < 33) {
        int bin = fb + tid;
        offs[tid] = (bin < NBINS) ? (cnt[bin * NB] + bsum[(bin * NB) >> 9]) : NNZV;
    }
    if (tid < 8) cur[tid] = 0;
    int r_lane = lane >> 2, q = lane & 3;
    float4 acc = make_float4(0.f, 0.f, 0.f, 0.f);
    float4 pf[8];
    {
        const float4* src = (const float4*)zuT + (size_t)(split * 32) * 4096;
#pragma unroll
        for (int r = 0; r < 8; ++r) pf[r] = src[r * 512 + tid];
    }
    __syncthreads();
#pragma unroll
    for (int r = 0; r < 8; ++r) ((float4*)stage)[r * 512 + tid] = pf[r];
    __syncthreads();
    for (int gi = 0; gi < 32; ++gi) {
        if (gi + 1 < 32) {
            const float4* src = (const float4*)zuT + (size_t)(split * 32 + gi + 1) * 4096;
#pragma unroll
            for (int r = 0; r < 8; ++r) pf[r] = src[r * 512 + tid];
        }
        int i0 = offs[gi], i1 = offs[gi + 1];
        // --- scatter items into wave-owned segments (int atomics only) ---
        for (int i = i0 + tid; i < i1; i += 512) {
            uint2 e = items[i];
            int rg = (int)((e.y >> 4) & 7u);
            int p = atomicAdd(&cur[rg], 1);
            if (p < CAP2) seg[rg][p] = e;
        }
        __syncthreads();
        // --- wave-serial broadcast reduce of seg[wid] ---
        int cw = cur[wid]; if (cw > CAP2) cw = CAP2;
        for (int j = 0; j < cw; ++j) {
            uint2 e = seg[wid][j];
            float v = __uint_as_float(e.x);
            float vm = ((int)(e.y & 15u) == r_lane) ? v : 0.f;
            int gl = (int)(e.y >> 7);
            float4 x = ((const float4*)stage)[gl * 4 + q];
            acc.x += vm * x.x; acc.y += vm * x.y; acc.z += vm * x.z; acc.w += vm * x.w;
        }
        __syncthreads();                               // done reading stage & seg
        if (tid < 8) cur[tid] = 0;
        if (gi + 1 < 32) {
#pragma unroll
            for (int r = 0; r < 8; ++r) ((float4*)stage)[r * 512 + tid] = pf[r];
        }
        __syncthreads();                               // stage ready, cursors zeroed
    }
    ((float4*)part)[((stile * 2 + split) * 128 + wid * 16 + r_lane) * 4 + q] = acc;
}

// ---------------- col-pass accumulate: batch-half split, direct t2T ---------
// 512 blocks = 256 stiles x 2 batch-halves; wave w owns cols [w*32, w*32+32);
// lane = (col&31)*2 + h; this block handles quads {2*bh, 2*bh+1}.
__global__ __launch_bounds__(512) void k_accumC(const uint2* __restrict__ items,
                                                const int* __restrict__ cnt,
                                                const int* __restrict__ bsum,
                                                const float* __restrict__ rT,
                                                float* __restrict__ t2T) {
    __shared__ __align__(16) float stage[512 * 16];    // 32 KB
    __shared__ uint2 seg[8][CAP2];
    __shared__ int cur[8];
    __shared__ int offs[33];
    int tid = threadIdx.x, wid = tid >> 6, lane = tid & 63;
    int stile = blockIdx.x >> 1, bh = blockIdx.x & 1;
    int fb = stile * 32;
    if (tid < 33) {
        int bin = fb + tid;
        offs[tid] = (bin < NBINS) ? (cnt[bin * NB] + bsum[(bin * NB) >> 9]) : NNZV;
    }
    if (tid < 8) cur[tid] = 0;
    int c_lane = lane >> 1, h = lane & 1, qsel = 2 * bh + h;
    float4 acc = make_float4(0.f, 0.f, 0.f, 0.f);
    float4 pf[4];
    {
        const float4* src = (const float4*)rT;
#pragma unroll
        for (int r = 0; r < 4; ++r) pf[r] = src[r * 512 + tid];
    }
    __syncthreads();
#pragma unroll
    for (int r = 0; r < 4; ++r) ((float4*)stage)[r * 512 + tid] = pf[r];
    __syncthreads();
    for (int gi = 0; gi < 32; ++gi) {
        if (gi + 1 < 32) {
            const float4* src = (const float4*)rT + (size_t)(gi + 1) * 2048;
#pragma unroll
            for (int r = 0; r < 4; ++r) pf[r] = src[r * 512 + tid];
        }
        int i0 = offs[gi], i1 = offs[gi + 1];
        for (int i = i0 + tid; i < i1; i += 512) {
            uint2 e = items[i];
            int rg = (int)((e.y >> 5) & 7u);
            int p = atomicAdd(&cur[rg], 1);
            if (p < CAP2) seg[rg][p] = e;
        }
        __syncthreads();
        int cw = cur[wid]; if (cw > CAP2) cw = CAP2;
        for (int j = 0; j < cw; ++j) {
            uint2 e = seg[wid][j];
            float v = __uint_as_float(e.x);
            float vm = ((int)(e.y & 31u) == c_lane) ? v : 0.f;
            int gl = (int)(e.y >> 8);
            float4 x = ((const float4*)stage)[gl * 4 + qsel];
            acc.x += vm * x.x; acc.y += vm * x.y; acc.z += vm * x.z; acc.w += vm * x.w;
        }
        __syncthreads();
        if (tid < 8) cur[tid] = 0;
        if (gi + 1 < 32) {
#pragma unroll
            for (int r = 0; r < 4; ++r) ((float4*)stage)[r * 512 + tid] = pf[r];
        }
        __syncthreads();
    }
    int col = stile * 256 + wid * 32 + c_lane;
    ((float4*)t2T)[col * 4 + qsel] = acc;
}

// ---------------- rT[m*16+b] = y[b,m] - sum_splits part ----------------
__global__ __launch_bounds__(256) void k_reduce_rT(const float* __restrict__ y,
                                                   const float* __restrict__ part,
                                                   float* __restrict__ rT) {
    int id = blockIdx.x * 256 + threadIdx.x;   // 65536 float4 units
    int m = id >> 2, q = id & 3;
    int stile = m >> 7, l = m & 127;
    const float4* p4 = (const float4*)part;
    float4 s0 = p4[((stile * 2 + 0) * 128 + l) * 4 + q];
    float4 s1 = p4[((stile * 2 + 1) * 128 + l) * 4 + q];
    float4 o;
    o.x = y[(size_t)(4 * q + 0) * MM + m] - (s0.x + s1.x);
    o.y = y[(size_t)(4 * q + 1) * MM + m] - (s0.y + s1.y);
    o.z = y[(size_t)(4 * q + 2) * MM + m] - (s0.z + s1.z);
    o.w = y[(size_t)(4 * q + 3) * MM + m] - (s0.w + s1.w);
    ((float4*)rT)[m * 4 + q] = o;
}

// ---------------- per-block norm partials: NO contended atomics ----------
__global__ __launch_bounds__(256) void k_norm(const float* __restrict__ u,
                                              const float* __restrict__ t2T,
                                              float* __restrict__ partials) {
    __shared__ float wsum[4][BB];
    int n = blockIdx.x * 256 + threadIdx.x;
    float t[BB];
#pragma unroll
    for (int i = 0; i < 4; ++i)
        ((float4*)t)[i] = ((const float4*)(t2T + (size_t)n * BB))[i];
    float acc[BB];
#pragma unroll
    for (int b = 0; b < BB; ++b) {
        float v = u[(size_t)b * NN + n] * t[b];
        acc[b] = v * v;
    }
#pragma unroll
    for (int b = 0; b < BB; ++b) {
#pragma unroll
        for (int off = 32; off; off >>= 1)
            acc[b] += __shfl_xor(acc[b], off, 64);
    }
    int wid = threadIdx.x >> 6, lane = threadIdx.x & 63;
    if (lane < BB) wsum[wid][lane] = acc[lane];
    __syncthreads();
    if (threadIdx.x < BB) {
        float s = wsum[0][threadIdx.x] + wsum[1][threadIdx.x]
                + wsum[2][threadIdx.x] + wsum[3][threadIdx.x];
        partials[blockIdx.x * BB + threadIdx.x] = s;
    }
}

// ---------------- final norm reduce: 256 partial vectors -> norm2[16] ------
__global__ __launch_bounds__(256) void k_normfin(const float* __restrict__ partials,
                                                 float* __restrict__ norm2) {
    __shared__ float s[256];
    int tid = threadIdx.x;
    int b = tid & 15, grp = tid >> 4;
    float a = 0.f;
    for (int i = grp; i < 256; i += 16) a += partials[i * BB + b];
    s[tid] = a;
    __syncthreads();
    if (tid < BB) {
        float t = 0.f;
#pragma unroll
        for (int g = 0; g < 16; ++g) t += s[g * 16 + tid];
        norm2[tid] = t;
    }
}

// ---------------- out[b,n] = z - eta * v / max(1,||v||) ----------------
__global__ void k_final(const float* __restrict__ z, const float* __restrict__ u,
                        const float* __restrict__ t2T, const float* __restrict__ norm2,
                        const float* __restrict__ eta, float* __restrict__ out) {
    int n = blockIdx.x * 256 + threadIdx.x;
    float t[BB];
#pragma unroll
    for (int i = 0; i < 4; ++i)
        ((float4*)t)[i] = ((const float4*)(t2T + (size_t)n * BB))[i];
    float e = eta[0];
#pragma unroll
    for (int b = 0; b < BB; ++b) {
        float denom = fmaxf(1.0f, sqrtf(norm2[b]));
        float v = u[(size_t)b * NN + n] * t[b];
        out[(size_t)b * NN + n] = z[(size_t)b * NN + n] - e * v / denom;
    }
}

extern "C" void kernel_launch(void* const* d_in, const int* in_sizes, int n_in,
                              void* d_out, int out_size, void* d_ws, size_t ws_size,
                              hipStream_t stream) {
    const float* z      = (const float*)d_in[0];
    const float* u      = (const float*)d_in[1];
    const float* y      = (const float*)d_in[2];
    const float* A_vals = (const float*)d_in[3];
    const int*   A_rows = (const int*)d_in[4];
    const int*   A_cols = (const int*)d_in[5];
    const float* eta    = (const float*)d_in[6];
    float* out = (float*)d_out;

    char* ws = (char*)d_ws;
    float* norm2 = (float*)(ws);                       // 64 B
    float* nparts = (float*)(ws + 256);                // 16 KB (256*16 floats)
    int*   bsum  = (int*)  (ws + 65536);               // 4 KB (1024 ints)
    float* r0    = (float*)(ws + (1u << 20));          // 4 MB: zuT, later t2T
    float* rT    = (float*)(ws + (5u << 20));          // 1 MB
    float* part  = (float*)(ws + (6u << 20));          // 2 MB row partials
    int*   cnt   = (int*)  (ws + (8u << 20));          // 2 MB (8192*64 ints)
    uint2* items = (uint2*)(ws + (10u << 20));         // 33.55 MB

    // ---- t1 = A(zu): scatter rows (stile 128), gather cols (gtile 1024) ----
    k_zuT<<<NN / 256, 256, 0, stream>>>(z, u, r0);
    k_hist<<<NB, 512, 0, stream>>>(A_rows, A_cols, cnt, 7, 10, 64);
    k_scanA<<<1024, 512, 0, stream>>>(cnt, bsum);
    k_scanB<<<1, 1024, 0, stream>>>(bsum);
    k_scatter<<<NB, 512, 0, stream>>>(A_rows, A_cols, A_vals, cnt, bsum,
                                      7, 10, 64, 127, 1023, 7, items);
    k_accumR<<<256, 512, 0, stream>>>(items, cnt, bsum, r0, part);
    k_reduce_rT<<<256, 256, 0, stream>>>(y, part, rT);

    // ---- t2 = A^T(r): scatter cols (stile 256), gather rows (gtile 512) ----
    k_hist<<<NB, 512, 0, stream>>>(A_cols, A_rows, cnt, 8, 9, 32);
    k_scanA<<<1024, 512, 0, stream>>>(cnt, bsum);
    k_scanB<<<1, 1024, 0, stream>>>(bsum);
    k_scatter<<<NB, 512, 0, stream>>>(A_cols, A_rows, A_vals, cnt, bsum,
                                      8, 9, 32, 255, 511, 8, items);
    k_accumC<<<512, 512, 0, stream>>>(items, cnt, bsum, rT, r0);

    // ---- norm + final ----
    k_norm<<<NN / 256, 256, 0, stream>>>(u, r0, nparts);
    k_normfin<<<1, 256, 0, stream>>>(nparts, norm2);
    k_final<<<NN / 256, 256, 0, stream>>>(z, u, r0, norm2, eta, out);
}

// Round 11
// 834.170 us; speedup vs baseline: 1.1735x; 1.1735x over previous
//
#include <hip/hip_runtime.h>
#include <hip/hip_bf16.h>

#define MM   16384
#define NN   65536
#define NNZV 4194304
#define BB   16

#define NB    64                 // hist/scatter blocks
#define IPT   128                // NNZV / (NB*512)
#define NBINS 8192               // bins per pass (both passes)
#define CAP   896                // sortbuf capacity (avg bucket = 512, +17 sigma)

// row pass: t1 = A(zu): scatter M (stile 128 rows, 128 stiles x 2 gather-splits),
//           gather N (gtile 1024, 64 gtiles)
// col pass: t2 = A^T(r): scatter N (stile 256 cols), gather M (gtile 512, 32 gtiles)

// ---------------- zuT[n*16+b] = z[b,n]*u[b,n] ----------------
__global__ void k_zuT(const float* __restrict__ z, const float* __restrict__ u,
                      float* __restrict__ zuT) {
    int n = blockIdx.x * 256 + threadIdx.x;
    float f[BB];
#pragma unroll
    for (int b = 0; b < BB; ++b)
        f[b] = z[(size_t)b * NN + n] * u[(size_t)b * NN + n];
#pragma unroll
    for (int i = 0; i < 4; ++i)
        ((float4*)(zuT + (size_t)n * BB))[i] = ((float4*)f)[i];
}

// ---------------- 2D histogram: bin = (s>>ss)*ngt + (g>>gs) ----------------
__global__ __launch_bounds__(512) void k_hist(const int* __restrict__ sidx,
                                              const int* __restrict__ gidx,
                                              int* __restrict__ cnt,
                                              int ss, int gs, int ngt) {
    __shared__ int h[NBINS];
    for (int i = threadIdx.x; i < NBINS; i += 512) h[i] = 0;
    __syncthreads();
    int base = blockIdx.x * (512 * IPT);
    for (int it = 0; it < IPT; ++it) {
        int k = base + it * 512 + threadIdx.x;
        int bin = (sidx[k] >> ss) * ngt + (gidx[k] >> gs);
        atomicAdd(&h[bin], 1);
    }
    __syncthreads();
    for (int i = threadIdx.x; i < NBINS; i += 512)
        cnt[i * NB + blockIdx.x] = h[i];
}

// ---------------- scan phase A: per-512-chunk exclusive scan ----------------
__global__ __launch_bounds__(512) void k_scanA(int* __restrict__ cnt, int* __restrict__ bsum) {
    __shared__ int s[512];
    int tid = threadIdx.x;
    int v = cnt[blockIdx.x * 512 + tid];
    s[tid] = v;
    __syncthreads();
    for (int off = 1; off < 512; off <<= 1) {
        int t = (tid >= off) ? s[tid - off] : 0;
        __syncthreads();
        s[tid] += t;
        __syncthreads();
    }
    cnt[blockIdx.x * 512 + tid] = s[tid] - v;
    if (tid == 511) bsum[blockIdx.x] = s[511];
}

// ---------------- scan phase B: exclusive scan of 1024 chunk sums ----------
__global__ __launch_bounds__(1024) void k_scanB(int* __restrict__ bsum) {
    __shared__ int s[1024];
    int tid = threadIdx.x;
    int v = bsum[tid];
    s[tid] = v;
    __syncthreads();
    for (int off = 1; off < 1024; off <<= 1) {
        int t = (tid >= off) ? s[tid - off] : 0;
        __syncthreads();
        s[tid] += t;
        __syncthreads();
    }
    bsum[tid] = s[tid] - v;
}

// ---------------- scatter into (stile,gtile) buckets ----------------
// item = (val bits, (g_local << shl) | s_local)
__global__ __launch_bounds__(512) void k_scatter(const int* __restrict__ sidx,
                                                 const int* __restrict__ gidx,
                                                 const float* __restrict__ vals,
                                                 const int* __restrict__ cnt,
                                                 const int* __restrict__ bsum,
                                                 int ss, int gs, int ngt,
                                                 int smask, int gmask, int shl,
                                                 uint2* __restrict__ items) {
    __shared__ int nxt[NBINS];
    for (int i = threadIdx.x; i < NBINS; i += 512) {
        int idx = i * NB + blockIdx.x;
        nxt[i] = cnt[idx] + bsum[idx >> 9];
    }
    __syncthreads();
    int base = blockIdx.x * (512 * IPT);
    for (int it = 0; it < IPT; ++it) {
        int k = base + it * 512 + threadIdx.x;
        int s = sidx[k], g = gidx[k];
        float v = vals[k];
        int bin = (s >> ss) * ngt + (g >> gs);
        int r = atomicAdd(&nxt[bin], 1);
        items[r] = make_uint2(__float_as_uint(v),
                              ((unsigned)(g & gmask) << shl) | (unsigned)(s & smask));
    }
}

// ---------------- row-pass accumulate: zero f32 atomics, reg-owned rows ----
// 512 threads: thread = (row 0..127, quad 0..3). part[stile][split][128][16].
// __launch_bounds__(512,4): VGPR cap 128 so the pf[8] prefetch stays in
// registers (52-VGPR build spilled it -> ~305 MB of scratch writebacks).
__global__ __launch_bounds__(512, 4) void k_accumR(const uint2* __restrict__ items,
                                                   const int* __restrict__ cnt,
                                                   const int* __restrict__ bsum,
                                                   const float* __restrict__ zuT,
                                                   float* __restrict__ part) {
    __shared__ __align__(16) float stage[1024 * 16];   // 64 KB: one gather tile
    __shared__ uint2 sortbuf[CAP];
    __shared__ int hist[128], starts[129], cursors[128], offs[33];
    int tid = threadIdx.x;
    int stile = blockIdx.x >> 1, split = blockIdx.x & 1;
    int fb = stile * 64 + split * 32;                  // first bin of this block
    if (tid < 33) {
        int bin = fb + tid;
        offs[tid] = (bin < NBINS) ? (cnt[bin * NB] + bsum[(bin * NB) >> 9]) : NNZV;
    }
    int r_row = tid >> 2, q = tid & 3;
    float4 acc = make_float4(0.f, 0.f, 0.f, 0.f);
    float4 pf[8];
    {   // preload gather tile 0 (coalesced)
        const float4* src = (const float4*)zuT + (size_t)(split * 32) * 4096;
#pragma unroll
        for (int r = 0; r < 8; ++r) pf[r] = src[r * 512 + tid];
    }
    __syncthreads();                                   // offs ready
#pragma unroll
    for (int r = 0; r < 8; ++r) ((float4*)stage)[r * 512 + tid] = pf[r];
    __syncthreads();
    for (int gi = 0; gi < 32; ++gi) {
        if (gi + 1 < 32) {                             // issue next-tile loads early (T14)
            const float4* src = (const float4*)zuT + (size_t)(split * 32 + gi + 1) * 4096;
#pragma unroll
            for (int r = 0; r < 8; ++r) pf[r] = src[r * 512 + tid];
        }
        int i0 = offs[gi], i1 = offs[gi + 1];
        // --- histogram by local row (int LDS atomics only) ---
        if (tid < 128) hist[tid] = 0;
        __syncthreads();
        uint2 e0; bool have = (i0 + tid < i1);
        if (have) { e0 = items[i0 + tid]; atomicAdd(&hist[e0.y & 127u], 1); }
        for (int i = i0 + tid + 512; i < i1; i += 512)
            atomicAdd(&hist[items[i].y & 127u], 1);
        __syncthreads();
        // --- exclusive scan (wave 0) ---
        if (tid < 64) {
            int b0 = tid * 2;
            int h0 = hist[b0], h1 = hist[b0 + 1];
            int s = h0 + h1, incl = s;
#pragma unroll
            for (int off = 1; off < 64; off <<= 1) {
                int v = __shfl_up(incl, off, 64);
                if (tid >= off) incl += v;
            }
            int excl = incl - s;
            starts[b0] = excl;      starts[b0 + 1] = excl + h0;
            cursors[b0] = excl;     cursors[b0 + 1] = excl + h0;
            if (tid == 63) starts[128] = incl;
        }
        __syncthreads();
        // --- scatter into row-sorted sortbuf ---
        if (have) {
            int r = atomicAdd(&cursors[e0.y & 127u], 1);
            if (r < CAP) sortbuf[r] = e0;
        }
        for (int i = i0 + tid + 512; i < i1; i += 512) {
            uint2 e = items[i];
            int r = atomicAdd(&cursors[e.y & 127u], 1);
            if (r < CAP) sortbuf[r] = e;
        }
        __syncthreads();
        // --- segmented reduce: exclusive row/quad ownership, registers ---
        int js = starts[r_row], je = starts[r_row + 1];
        for (int j = js; j < je; ++j) {
            uint2 e = sortbuf[j];
            float v = __uint_as_float(e.x);
            int gl = (int)(e.y >> 7);
            float4 x = ((const float4*)stage)[gl * 4 + q];
            acc.x += v * x.x; acc.y += v * x.y; acc.z += v * x.z; acc.w += v * x.w;
        }
        __syncthreads();                               // done reading stage/sortbuf
        if (gi + 1 < 32) {
#pragma unroll
            for (int r = 0; r < 8; ++r) ((float4*)stage)[r * 512 + tid] = pf[r];
        }
        __syncthreads();
    }
    ((float4*)part)[((stile * 2 + split) * 128 + r_row) * 4 + q] = acc;
}

// ---------------- col-pass accumulate: 256 rows x 2 halves, writes t2T ------
__global__ __launch_bounds__(512, 4) void k_accumC(const uint2* __restrict__ items,
                                                   const int* __restrict__ cnt,
                                                   const int* __restrict__ bsum,
                                                   const float* __restrict__ rT,
                                                   float* __restrict__ t2T) {
    __shared__ __align__(16) float stage[512 * 16];    // 32 KB
    __shared__ uint2 sortbuf[CAP];
    __shared__ int hist[256], starts[257], cursors[256], offs[33];
    int tid = threadIdx.x;
    int stile = blockIdx.x;
    int fb = stile * 32;
    if (tid < 33) {
        int bin = fb + tid;
        offs[tid] = (bin < NBINS) ? (cnt[bin * NB] + bsum[(bin * NB) >> 9]) : NNZV;
    }
    int r_row = tid >> 1, hh = tid & 1;
    float4 acc0 = make_float4(0.f, 0.f, 0.f, 0.f);
    float4 acc1 = make_float4(0.f, 0.f, 0.f, 0.f);
    float4 pf[4];
    {
        const float4* src = (const float4*)rT;
#pragma unroll
        for (int r = 0; r < 4; ++r) pf[r] = src[r * 512 + tid];
    }
    __syncthreads();
#pragma unroll
    for (int r = 0; r < 4; ++r) ((float4*)stage)[r * 512 + tid] = pf[r];
    __syncthreads();
    for (int gi = 0; gi < 32; ++gi) {
        if (gi + 1 < 32) {
            const float4* src = (const float4*)rT + (size_t)(gi + 1) * 2048;
#pragma unroll
            for (int r = 0; r < 4; ++r) pf[r] = src[r * 512 + tid];
        }
        int i0 = offs[gi], i1 = offs[gi + 1];
        if (tid < 256) hist[tid] = 0;
        __syncthreads();
        uint2 e0; bool have = (i0 + tid < i1);
        if (have) { e0 = items[i0 + tid]; atomicAdd(&hist[e0.y & 255u], 1); }
        for (int i = i0 + tid + 512; i < i1; i += 512)
            atomicAdd(&hist[items[i].y & 255u], 1);
        __syncthreads();
        if (tid < 64) {
            int b0 = tid * 4;
            int h0 = hist[b0], h1 = hist[b0 + 1], h2 = hist[b0 + 2], h3 = hist[b0 + 3];
            int s = h0 + h1 + h2 + h3, incl = s;
#pragma unroll
            for (int off = 1; off < 64; off <<= 1) {
                int v = __shfl_up(incl, off, 64);
                if (tid >= off) incl += v;
            }
            int excl = incl - s;
            starts[b0] = excl;          starts[b0 + 1] = excl + h0;
            starts[b0 + 2] = excl + h0 + h1; starts[b0 + 3] = excl + h0 + h1 + h2;
            cursors[b0] = starts[b0];   cursors[b0 + 1] = starts[b0 + 1];
            cursors[b0 + 2] = starts[b0 + 2]; cursors[b0 + 3] = starts[b0 + 3];
            if (tid == 63) starts[256] = incl;
        }
        __syncthreads();
        if (have) {
            int r = atomicAdd(&cursors[e0.y & 255u], 1);
            if (r < CAP) sortbuf[r] = e0;
        }
        for (int i = i0 + tid + 512; i < i1; i += 512) {
            uint2 e = items[i];
            int r = atomicAdd(&cursors[e.y & 255u], 1);
            if (r < CAP) sortbuf[r] = e;
        }
        __syncthreads();
        int js = starts[r_row], je = starts[r_row + 1];
        for (int j = js; j < je; ++j) {
            uint2 e = sortbuf[j];
            float v = __uint_as_float(e.x);
            int gl = (int)(e.y >> 8);
            float4 x0 = ((const float4*)stage)[gl * 4 + 2 * hh];
            float4 x1 = ((const float4*)stage)[gl * 4 + 2 * hh + 1];
            acc0.x += v * x0.x; acc0.y += v * x0.y; acc0.z += v * x0.z; acc0.w += v * x0.w;
            acc1.x += v * x1.x; acc1.y += v * x1.y; acc1.z += v * x1.z; acc1.w += v * x1.w;
        }
        __syncthreads();
        if (gi + 1 < 32) {
#pragma unroll
            for (int r = 0; r < 4; ++r) ((float4*)stage)[r * 512 + tid] = pf[r];
        }
        __syncthreads();
    }
    ((float4*)t2T)[(stile * 256 + r_row) * 4 + 2 * hh]     = acc0;
    ((float4*)t2T)[(stile * 256 + r_row) * 4 + 2 * hh + 1] = acc1;
}

// ---------------- rT[m*16+b] = y[b,m] - sum_splits part ----------------
__global__ __launch_bounds__(256) void k_reduce_rT(const float* __restrict__ y,
                                                   const float* __restrict__ part,
                                                   float* __restrict__ rT) {
    int id = blockIdx.x * 256 + threadIdx.x;   // 65536 float4 units
    int m = id >> 2, q = id & 3;
    int stile = m >> 7, l = m & 127;
    const float4* p4 = (const float4*)part;
    float4 s0 = p4[((stile * 2 + 0) * 128 + l) * 4 + q];
    float4 s1 = p4[((stile * 2 + 1) * 128 + l) * 4 + q];
    float4 o;
    o.x = y[(size_t)(4 * q + 0) * MM + m] - (s0.x + s1.x);
    o.y = y[(size_t)(4 * q + 1) * MM + m] - (s0.y + s1.y);
    o.z = y[(size_t)(4 * q + 2) * MM + m] - (s0.z + s1.z);
    o.w = y[(size_t)(4 * q + 3) * MM + m] - (s0.w + s1.w);
    ((float4*)rT)[m * 4 + q] = o;
}

// ---------------- per-block norm partials: NO contended atomics ----------
__global__ __launch_bounds__(256) void k_norm(const float* __restrict__ u,
                                              const float* __restrict__ t2T,
                                              float* __restrict__ partials) {
    __shared__ float wsum[4][BB];
    int n = blockIdx.x * 256 + threadIdx.x;
    float t[BB];
#pragma unroll
    for (int i = 0; i < 4; ++i)
        ((float4*)t)[i] = ((const float4*)(t2T + (size_t)n * BB))[i];
    float acc[BB];
#pragma unroll
    for (int b = 0; b < BB; ++b) {
        float v = u[(size_t)b * NN + n] * t[b];
        acc[b] = v * v;
    }
#pragma unroll
    for (int b = 0; b < BB; ++b) {
#pragma unroll
        for (int off = 32; off; off >>= 1)
            acc[b] += __shfl_xor(acc[b], off, 64);
    }
    int wid = threadIdx.x >> 6, lane = threadIdx.x & 63;
    if (lane < BB) wsum[wid][lane] = acc[lane];
    __syncthreads();
    if (threadIdx.x < BB) {
        float s = wsum[0][threadIdx.x] + wsum[1][threadIdx.x]
                + wsum[2][threadIdx.x] + wsum[3][threadIdx.x];
        partials[blockIdx.x * BB + threadIdx.x] = s;
    }
}

// ---------------- final norm reduce: 256 partial vectors -> norm2[16] ------
__global__ __launch_bounds__(256) void k_normfin(const float* __restrict__ partials,
                                                 float* __restrict__ norm2) {
    __shared__ float s[256];
    int tid = threadIdx.x;
    int b = tid & 15, grp = tid >> 4;
    float a = 0.f;
    for (int i = grp; i < 256; i += 16) a += partials[i * BB + b];
    s[tid] = a;
    __syncthreads();
    if (tid < BB) {
        float t = 0.f;
#pragma unroll
        for (int g = 0; g < 16; ++g) t += s[g * 16 + tid];
        norm2[tid] = t;
    }
}

// ---------------- out[b,n] = z - eta * v / max(1,||v||) ----------------
__global__ void k_final(const float* __restrict__ z, const float* __restrict__ u,
                        const float* __restrict__ t2T, const float* __restrict__ norm2,
                        const float* __restrict__ eta, float* __restrict__ out) {
    int n = blockIdx.x * 256 + threadIdx.x;
    float t[BB];
#pragma unroll
    for (int i = 0; i < 4; ++i)
        ((float4*)t)[i] = ((const float4*)(t2T + (size_t)n * BB))[i];
    float e = eta[0];
#pragma unroll
    for (int b = 0; b < BB; ++b) {
        float denom = fmaxf(1.0f, sqrtf(norm2[b]));
        float v = u[(size_t)b * NN + n] * t[b];
        out[(size_t)b * NN + n] = z[(size_t)b * NN + n] - e * v / denom;
    }
}

extern "C" void kernel_launch(void* const* d_in, const int* in_sizes, int n_in,
                              void* d_out, int out_size, void* d_ws, size_t ws_size,
                              hipStream_t stream) {
    const float* z      = (const float*)d_in[0];
    const float* u      = (const float*)d_in[1];
    const float* y      = (const float*)d_in[2];
    const float* A_vals = (const float*)d_in[3];
    const int*   A_rows = (const int*)d_in[4];
    const int*   A_cols = (const int*)d_in[5];
    const float* eta    = (const float*)d_in[6];
    float* out = (float*)d_out;

    char* ws = (char*)d_ws;
    float* norm2 = (float*)(ws);                       // 64 B
    float* nparts = (float*)(ws + 256);                // 16 KB (256*16 floats)
    int*   bsum  = (int*)  (ws + 65536);               // 4 KB (1024 ints)
    float* r0    = (float*)(ws + (1u << 20));          // 4 MB: zuT, later t2T
    float* rT    = (float*)(ws + (5u << 20));          // 1 MB
    float* part  = (float*)(ws + (6u << 20));          // 2 MB row partials
    int*   cnt   = (int*)  (ws + (8u << 20));          // 2 MB (8192*64 ints)
    uint2* items = (uint2*)(ws + (10u << 20));         // 33.55 MB

    // ---- t1 = A(zu): scatter rows (stile 128), gather cols (gtile 1024) ----
    k_zuT<<<NN / 256, 256, 0, stream>>>(z, u, r0);
    k_hist<<<NB, 512, 0, stream>>>(A_rows, A_cols, cnt, 7, 10, 64);
    k_scanA<<<1024, 512, 0, stream>>>(cnt, bsum);
    k_scanB<<<1, 1024, 0, stream>>>(bsum);
    k_scatter<<<NB, 512, 0, stream>>>(A_rows, A_cols, A_vals, cnt, bsum,
                                      7, 10, 64, 127, 1023, 7, items);
    k_accumR<<<256, 512, 0, stream>>>(items, cnt, bsum, r0, part);
    k_reduce_rT<<<256, 256, 0, stream>>>(y, part, rT);

    // ---- t2 = A^T(r): scatter cols (stile 256), gather rows (gtile 512) ----
    k_hist<<<NB, 512, 0, stream>>>(A_cols, A_rows, cnt, 8, 9, 32);
    k_scanA<<<1024, 512, 0, stream>>>(cnt, bsum);
    k_scanB<<<1, 1024, 0, stream>>>(bsum);
    k_scatter<<<NB, 512, 0, stream>>>(A_cols, A_rows, A_vals, cnt, bsum,
                                      8, 9, 32, 255, 511, 8, items);
    k_accumC<<<256, 512, 0, stream>>>(items, cnt, bsum, rT, r0);

    // ---- norm + final ----
    k_norm<<<NN / 256, 256, 0, stream>>>(u, r0, nparts);
    k_normfin<<<1, 256, 0, stream>>>(nparts, norm2);
    k_final<<<NN / 256, 256, 0, stream>>>(z, u, r0, norm2, eta, out);
}